// Round 1
// baseline (14096.666 us; speedup 1.0000x reference)
//
#include <hip/hip_runtime.h>
#include <cfloat>
#include <cstdint>

#define DIM 256
#define KCODES 1024
#define NVEC 32768
#define THRESH 2e-4f

// ws layout (floats):
// [0]      Csq[1024]
// [1024]   A[32768]
// [33792]  idx[32768] (int)
// [66560]  flagCount (int) + pad
// [66576]  flagList[32768] (int)

__global__ __launch_bounds__(256) void precompute_kernel(
    const float* __restrict__ z, const float* __restrict__ emb,
    float* __restrict__ Csq, float* __restrict__ A, int* __restrict__ flagCount) {
  int blk = blockIdx.x, tid = threadIdx.x;
  if (blk < 512) {
    // ||z_n||^2 for 64 vectors, fp32-squared terms summed in fp64 then rounded
    int n0 = blk * 64;
    int b = n0 >> 10, wh0 = n0 & 1023;
    int v = tid & 63, g = tid >> 6;
    double acc = 0.0;
    for (int c = g; c < DIM; c += 4) {
      float x = z[((size_t)(b * DIM + c) << 10) + wh0 + v];
      float y = x * x;
      acc += (double)y;
    }
    __shared__ double rd[4][64];
    rd[g][v] = acc;
    __syncthreads();
    if (g == 0) {
      double s = rd[0][v] + rd[1][v] + rd[2][v] + rd[3][v];
      A[n0 + v] = (float)s;
    }
  } else if (blk < 516) {
    int k = (blk - 512) * 256 + tid;
    const float4* e4 = (const float4*)(emb + (size_t)k * DIM);
    double acc = 0.0;
    for (int d4 = 0; d4 < DIM / 4; ++d4) {
      float4 e = e4[d4];
      acc += (double)(e.x * e.x) + (double)(e.y * e.y) +
             (double)(e.z * e.z) + (double)(e.w * e.w);
    }
    Csq[k] = (float)acc;
  } else {
    if (tid == 0) *flagCount = 0;
  }
}

// Phase 1: fp32 distances s = C_k - 2*dot, track (min1,min2,idx); flag near-ties.
// Block: 32 vectors x 1024 codes. 256 threads = 16tx x 16ty.
// Thread owns vectors {ty, ty+16}, codes {tx+16j} per 64-code chunk.
__global__ __launch_bounds__(256) void phase1_kernel(
    const float* __restrict__ z, const float* __restrict__ emb,
    const float* __restrict__ Csq, int* __restrict__ idxbuf,
    int* __restrict__ flagCount, int* __restrict__ flagList) {
  __shared__ float zs[32][260];   // [vector][dim], pad keeps reads 2-way max
  __shared__ float es[64][68];    // [code][64-dim chunk]
  int tid = threadIdx.x;
  int blk = blockIdx.x;           // 1024 blocks
  int n0 = blk * 32;
  int b = n0 >> 10, wh0 = n0 & 1023;
  int tx = tid & 15, ty = tid >> 4;

  { // stage z tile: lanes over vectors (coalesced 128B), full D resident
    int v = tid & 31, g = tid >> 5;
    const float* zp = z + ((size_t)(b * DIM) << 10) + wh0 + v;
    for (int c = g; c < DIM; c += 8) zs[v][c] = zp[(size_t)c << 10];
  }

  float m1[2] = {FLT_MAX, FLT_MAX}, m2[2] = {FLT_MAX, FLT_MAX};
  int bi[2] = {0, 0};

  for (int cc = 0; cc < 16; ++cc) {
    float acc[2][4] = {};
    for (int dc = 0; dc < 4; ++dc) {
      __syncthreads();
      { // stage 64 codes x 64 dims of emb (row-contiguous 256B loads)
        int r0 = tid >> 4, x = tid & 15;
        const float* ep = emb + (size_t)(cc * 64) * DIM + dc * 64 + x * 4;
        for (int p = 0; p < 4; ++p) {
          int r = p * 16 + r0;
          float4 e = *(const float4*)(ep + (size_t)r * DIM);
          *(float4*)&es[r][x * 4] = e;
        }
      }
      __syncthreads();
      const float4* zr0 = (const float4*)&zs[ty][dc * 64];
      const float4* zr1 = (const float4*)&zs[ty + 16][dc * 64];
      const float4* er0 = (const float4*)&es[tx][0];
      const float4* er1 = (const float4*)&es[tx + 16][0];
      const float4* er2 = (const float4*)&es[tx + 32][0];
      const float4* er3 = (const float4*)&es[tx + 48][0];
      for (int d4 = 0; d4 < 16; ++d4) {
        float4 a0 = zr0[d4], a1 = zr1[d4];
        float4 b0 = er0[d4], b1 = er1[d4], b2 = er2[d4], b3 = er3[d4];
        acc[0][0] += a0.x*b0.x + a0.y*b0.y + a0.z*b0.z + a0.w*b0.w;
        acc[0][1] += a0.x*b1.x + a0.y*b1.y + a0.z*b1.z + a0.w*b1.w;
        acc[0][2] += a0.x*b2.x + a0.y*b2.y + a0.z*b2.z + a0.w*b2.w;
        acc[0][3] += a0.x*b3.x + a0.y*b3.y + a0.z*b3.z + a0.w*b3.w;
        acc[1][0] += a1.x*b0.x + a1.y*b0.y + a1.z*b0.z + a1.w*b0.w;
        acc[1][1] += a1.x*b1.x + a1.y*b1.y + a1.z*b1.z + a1.w*b1.w;
        acc[1][2] += a1.x*b2.x + a1.y*b2.y + a1.z*b2.z + a1.w*b2.w;
        acc[1][3] += a1.x*b3.x + a1.y*b3.y + a1.z*b3.z + a1.w*b3.w;
      }
    }
    // min update for this 64-code chunk
    for (int j = 0; j < 4; ++j) {
      int c = cc * 64 + tx + 16 * j;
      float Cc = Csq[c];
      for (int i = 0; i < 2; ++i) {
        float s = fmaf(-2.0f, acc[i][j], Cc);
        if (s < m1[i] || (s == m1[i] && c < bi[i])) {
          m2[i] = m1[i]; m1[i] = s; bi[i] = c;
        } else if (s < m2[i]) {
          m2[i] = s;
        }
      }
    }
  }

  // reduce across the 16 tx lanes sharing each vector (first-index tie-break)
  for (int i = 0; i < 2; ++i) {
    float M1 = m1[i], M2 = m2[i];
    int BI = bi[i];
    for (int off = 8; off > 0; off >>= 1) {
      float om1 = __shfl_xor(M1, off, 16);
      float om2 = __shfl_xor(M2, off, 16);
      int   obi = __shfl_xor(BI, off, 16);
      float lo = fminf(M2, om2);
      bool take = (om1 < M1) || (om1 == M1 && obi < BI);
      float loser = take ? M1 : om1;
      M2 = fminf(lo, loser);
      if (take) { M1 = om1; BI = obi; }
    }
    if (tx == 0) {
      int n = n0 + ty + 16 * i;
      idxbuf[n] = BI;
      if (M2 - M1 < THRESH) {
        int pos = atomicAdd(flagCount, 1);
        flagList[pos] = n;
      }
    }
  }
}

// Phase 2: exact re-rank of flagged vectors, emulating the reference fp32
// formula q = (A - 2*fp32(dot)) + C with fp64-exact dot, first-index argmin.
__global__ __launch_bounds__(256) void phase2_kernel(
    const float* __restrict__ z, const float* __restrict__ emb,
    const float* __restrict__ Csq, const float* __restrict__ A,
    int* __restrict__ idxbuf, const int* __restrict__ flagCount,
    const int* __restrict__ flagList) {
  __shared__ float zq[DIM];
  __shared__ float rv[256];
  __shared__ int   ri[256];
  int tid = threadIdx.x;
  int cnt = *flagCount;
  for (int f = blockIdx.x; f < cnt; f += gridDim.x) {
    int n = flagList[f];
    int b = n >> 10, wh = n & 1023;
    __syncthreads();
    zq[tid] = z[((size_t)(b * DIM + tid) << 10) + wh];
    __syncthreads();
    float An = A[n];
    float bq = FLT_MAX; int bk = 0;
    for (int r = 0; r < 4; ++r) {
      int k = tid + 256 * r;
      const float4* e4 = (const float4*)(emb + (size_t)k * DIM);
      double dot = 0.0;
      for (int d4 = 0; d4 < 64; ++d4) {
        float4 e = e4[d4];
        const float* zp = &zq[d4 * 4];
        dot += (double)zp[0] * e.x + (double)zp[1] * e.y +
               (double)zp[2] * e.z + (double)zp[3] * e.w;
      }
      float Bf = (float)dot;
      float q = (An - 2.0f * Bf) + Csq[k];
      if (q < bq || (q == bq && k < bk)) { bq = q; bk = k; }
    }
    rv[tid] = bq; ri[tid] = bk;
    __syncthreads();
    for (int s = 128; s > 0; s >>= 1) {
      if (tid < s) {
        float ov = rv[tid + s]; int oi = ri[tid + s];
        if (ov < rv[tid] || (ov == rv[tid] && oi < ri[tid])) {
          rv[tid] = ov; ri[tid] = oi;
        }
      }
      __syncthreads();
    }
    if (tid == 0) idxbuf[n] = ri[0];
  }
}

// Gather + transpose: out0[b][c][wh] = out1[...] = emb[idx[n]][c]; out2 = idx as float.
__global__ __launch_bounds__(256) void gather_kernel(
    const float* __restrict__ emb, const int* __restrict__ idxbuf,
    float* __restrict__ out) {
  __shared__ int sidx[32];
  __shared__ float se[DIM][34];   // [dim][vector], padded
  int tid = threadIdx.x;
  int blk = blockIdx.x;           // 1024 blocks of 32 vectors
  int n0 = blk * 32;
  int b = n0 >> 10, wh0 = n0 & 1023;
  float* out0 = out;
  float* out1 = out + 8388608;
  float* out2 = out + 16777216;
  if (tid < 32) {
    int ix = idxbuf[n0 + tid];
    sidx[tid] = ix;
    out2[n0 + tid] = (float)ix;
  }
  __syncthreads();
  { // stage the 32 gathered emb rows, transposed into LDS
    int v = tid >> 3, d8 = tid & 7;
    int row = sidx[v];
    const float4* e4 = (const float4*)(emb + (size_t)row * DIM);
    for (int it = 0; it < 8; ++it) {
      int d4 = it * 8 + d8;
      float4 e = e4[d4];
      se[d4 * 4 + 0][v] = e.x; se[d4 * 4 + 1][v] = e.y;
      se[d4 * 4 + 2][v] = e.z; se[d4 * 4 + 3][v] = e.w;
    }
  }
  __syncthreads();
  { // coalesced 128B stores along wh
    int v = tid & 31, cg = tid >> 5;
    for (int c = cg; c < DIM; c += 8) {
      float val = se[c][v];
      size_t o = ((size_t)(b * DIM + c) << 10) + wh0 + v;
      out0[o] = val;
      out1[o] = val;
    }
  }
}

extern "C" void kernel_launch(void* const* d_in, const int* in_sizes, int n_in,
                              void* d_out, int out_size, void* d_ws, size_t ws_size,
                              hipStream_t stream) {
  const float* z   = (const float*)d_in[0];
  const float* emb = (const float*)d_in[1];
  float* ws = (float*)d_ws;
  float* Csq = ws;
  float* A   = ws + 1024;
  int* idxbuf    = (int*)(ws + 1024 + 32768);
  int* flagCount = (int*)(ws + 1024 + 32768 + 32768);
  int* flagList  = flagCount + 16;

  precompute_kernel<<<517, 256, 0, stream>>>(z, emb, Csq, A, flagCount);
  phase1_kernel<<<1024, 256, 0, stream>>>(z, emb, Csq, idxbuf, flagCount, flagList);
  phase2_kernel<<<128, 256, 0, stream>>>(z, emb, Csq, A, idxbuf, flagCount, flagList);
  gather_kernel<<<1024, 256, 0, stream>>>(emb, idxbuf, (float*)d_out);
}

// Round 2
// 230.206 us; speedup vs baseline: 61.2350x; 61.2350x over previous
//
#include <hip/hip_runtime.h>
#include <cfloat>
#include <cstdint>

#define THRESH 5e-4f

typedef __attribute__((ext_vector_type(8))) short bfrag8;          // 8 bf16 (4 VGPR) MFMA A/B frag
typedef __attribute__((ext_vector_type(8))) unsigned short upk8;   // packing vector
typedef __attribute__((ext_vector_type(4))) float facc4;           // MFMA C/D frag

__device__ __forceinline__ unsigned short f2bf(float x) {
  unsigned int u = __float_as_uint(x);
  u += 0x7FFFu + ((u >> 16) & 1u);   // RNE
  return (unsigned short)(u >> 16);
}

// ws layout (float offsets):
// 0      Csq[1024]
// 1024   A[32768]           (||z||^2, written by phase1)
// 33792  idx[32768] (int)
// 66560  flagCount (int, +16 pad)
// 66576  flagList[32768] (int)
// 99344  ebf[262144] ushort (bf16 emb, 512 KB)

__global__ __launch_bounds__(256) void precompute_kernel(
    const float* __restrict__ emb, float* __restrict__ Csq,
    unsigned short* __restrict__ ebf, int* __restrict__ flagCount) {
  int blk = blockIdx.x, t = threadIdx.x;
  if (blk < 4) {
    int k = blk * 256 + t;
    const float4* e4 = (const float4*)(emb + ((size_t)k << 8));
    double acc = 0.0;
    for (int d4 = 0; d4 < 64; ++d4) {
      float4 e = e4[d4];
      acc += (double)(e.x * e.x) + (double)(e.y * e.y) +
             (double)(e.z * e.z) + (double)(e.w * e.w);
    }
    Csq[k] = (float)acc;
    if (blk == 0 && t == 0) *flagCount = 0;
  } else {
    int base = (blk - 4) * 32768;
    for (int i = base + t; i < base + 32768; i += 256) ebf[i] = f2bf(emb[i]);
  }
}

// Phase 1: bf16 MFMA GEMM-argmin. Block = 64 vectors x 1024 codes, 4 waves.
// Wave (wv,wn): 32 vectors x 64 codes per 128-code pass. s = (-2 z.e) + ||e||^2.
// A-tile za: bf16(-2z), XOR-swizzled rows (T2). Also emits A = ||z||^2.
__global__ __launch_bounds__(256, 2) void phase1_kernel(
    const float* __restrict__ z, const unsigned short* __restrict__ ebf,
    const float* __restrict__ Csq, float* __restrict__ A,
    int* __restrict__ idxbuf, int* __restrict__ flagCount,
    int* __restrict__ flagList) {
  __shared__ char za_s[64 * 512] __attribute__((aligned(16)));  // 32 KB bf16 A-tile, swizzled
  __shared__ char sbuf[33792] __attribute__((aligned(16)));     // zraw f32[128][66] / eb bf16[128][128]
  __shared__ float Cs[1024];
  __shared__ double nrm[4][64];
  __shared__ float mm1[2][2][32], mm2[2][2][32];
  __shared__ int mbi[2][2][32];

  int t = threadIdx.x;
  int n0 = blockIdx.x << 6;
  int b = n0 >> 10, wh0 = n0 & 1023;

  ((float4*)Cs)[t] = ((const float4*)Csq)[t];

  // ---- stage A: global z -> LDS transpose -> bf16(-2z) swizzled; norms for free
  float* zraw = (float*)sbuf;             // [128][66]
  int v_l = t & 63, cg = t >> 6;          // raw-load role: lanes over vectors
  int part = t & 3, vv = t >> 2;          // transpose role: 4 c-parts x 64 vectors
  double nacc = 0.0;
  for (int r = 0; r < 2; ++r) {
    __syncthreads();
    const float* zp = z + (((size_t)(b * 256 + r * 128 + cg * 32)) << 10) + wh0 + v_l;
    for (int m = 0; m < 32; ++m) zraw[(cg * 32 + m) * 66 + v_l] = zp[(size_t)m << 10];
    __syncthreads();
    for (int m = 0; m < 4; ++m) {
      int c0 = part * 32 + m * 8;
      upk8 pk;
#pragma unroll
      for (int j = 0; j < 8; ++j) {
        float x = zraw[(c0 + j) * 66 + vv];
        float y = x * x;
        nacc += (double)y;
        pk[j] = f2bf(-2.0f * x);
      }
      int bytecol = (r * 256 + c0 * 2) ^ ((vv & 7) << 4);
      *(upk8*)(za_s + (vv << 9) + bytecol) = pk;
    }
  }
  nrm[part][vv] = nacc;
  __syncthreads();
  if (t < 64) {
    double s = nrm[0][t] + nrm[1][t] + nrm[2][t] + nrm[3][t];
    A[n0 + t] = (float)s;
  }

  // ---- MFMA main loop
  char* ebc = sbuf;                        // bf16 [128 codes][128 dims], swizzled
  int w = t >> 6, l = t & 63;
  int wv = w & 1, wn = w >> 1;
  int lx = l & 15, lg = l >> 4;
  int sw = (lx & 7) << 4;                  // row&7 == lx&7 for all our rows/cols

  float m1[8], m2[8];
  int bi[8];
#pragma unroll
  for (int s8 = 0; s8 < 8; ++s8) { m1[s8] = FLT_MAX; m2[s8] = FLT_MAX; bi[s8] = 0; }

  for (int p = 0; p < 8; ++p) {
    int cp0 = p << 7;
    facc4 acc[2][4];
#pragma unroll
    for (int mi = 0; mi < 2; ++mi)
#pragma unroll
      for (int nj = 0; nj < 4; ++nj) {
        facc4 zf = {0.0f, 0.0f, 0.0f, 0.0f};
        acc[mi][nj] = zf;
      }
    for (int q = 0; q < 2; ++q) {
      __syncthreads();
#pragma unroll
      for (int i = 0; i < 8; ++i) {       // stage 128 codes x 64 dims (bf16)
        int cid = t + (i << 8);
        int cl = cid >> 4, wi = cid & 15;
        upk8 ev = *(const upk8*)(ebf + (((size_t)(cp0 + cl)) << 8) + (q << 7) + (wi << 3));
        *(upk8*)(ebc + (cl << 8) + ((wi << 4) ^ ((cl & 7) << 4))) = ev;
      }
      __syncthreads();
#pragma unroll
      for (int kk = 0; kk < 4; ++kk) {
        int ka = (q << 8) + (kk << 6) + (lg << 4);
        bfrag8 a0 = *(const bfrag8*)(za_s + ((wv * 32 + lx) << 9) + (ka ^ sw));
        bfrag8 a1 = *(const bfrag8*)(za_s + ((wv * 32 + 16 + lx) << 9) + (ka ^ sw));
        int kb = (kk << 6) + (lg << 4);
#pragma unroll
        for (int nj = 0; nj < 4; ++nj) {
          int c = wn * 64 + nj * 16 + lx;
          bfrag8 bv = *(const bfrag8*)(ebc + (c << 8) + (kb ^ sw));
          acc[0][nj] = __builtin_amdgcn_mfma_f32_16x16x32_bf16(a0, bv, acc[0][nj], 0, 0, 0);
          acc[1][nj] = __builtin_amdgcn_mfma_f32_16x16x32_bf16(a1, bv, acc[1][nj], 0, 0, 0);
        }
      }
    }
    // min-update: C/D frag (m89): col=lane&15 (code), row=lg*4+reg (vector)
    float csv[4];
#pragma unroll
    for (int nj = 0; nj < 4; ++nj) csv[nj] = Cs[cp0 + wn * 64 + nj * 16 + lx];
#pragma unroll
    for (int mi = 0; mi < 2; ++mi)
#pragma unroll
      for (int reg = 0; reg < 4; ++reg) {
        int s8 = mi * 4 + reg;
#pragma unroll
        for (int nj = 0; nj < 4; ++nj) {
          float sv = acc[mi][nj][reg] + csv[nj];
          int code = cp0 + wn * 64 + nj * 16 + lx;
          if (sv < m1[s8]) { m2[s8] = m1[s8]; m1[s8] = sv; bi[s8] = code; }
          else if (sv < m2[s8]) m2[s8] = sv;
        }
      }
  }

  // ---- reduce 16 lanes sharing each vector, then merge the two code-half waves
#pragma unroll
  for (int s8 = 0; s8 < 8; ++s8) {
    float M1 = m1[s8], M2 = m2[s8];
    int BI = bi[s8];
    for (int off = 8; off > 0; off >>= 1) {
      float om1 = __shfl_xor(M1, off, 16);
      float om2 = __shfl_xor(M2, off, 16);
      int obi = __shfl_xor(BI, off, 16);
      float lo = fminf(M2, om2);
      bool take = (om1 < M1) || (om1 == M1 && obi < BI);
      float loser = take ? M1 : om1;
      M2 = fminf(lo, loser);
      if (take) { M1 = om1; BI = obi; }
    }
    if (lx == 0) {
      int row = ((s8 >> 2) << 4) + (lg << 2) + (s8 & 3);
      mm1[wn][wv][row] = M1; mm2[wn][wv][row] = M2; mbi[wn][wv][row] = BI;
    }
  }
  __syncthreads();
  if (wn == 0 && lx == 0) {
#pragma unroll
    for (int s8 = 0; s8 < 8; ++s8) {
      int row = ((s8 >> 2) << 4) + (lg << 2) + (s8 & 3);
      float a1v = mm1[0][wv][row], a2v = mm2[0][wv][row];
      int ab = mbi[0][wv][row];
      float b1v = mm1[1][wv][row], b2v = mm2[1][wv][row];
      int bb = mbi[1][wv][row];
      bool tb = (b1v < a1v) || (b1v == a1v && bb < ab);
      float M1 = tb ? b1v : a1v;
      int BI = tb ? bb : ab;
      float M2 = fminf(fminf(a2v, b2v), tb ? a1v : b1v);
      int n = n0 + wv * 32 + row;
      idxbuf[n] = BI;
      if (M2 - M1 < THRESH) {
        int pos = atomicAdd(flagCount, 1);
        flagList[pos] = n;
      }
    }
  }
}

// Phase 2: exact re-rank of flagged vectors (reference-formula emulation),
// batched 8 vectors per block iteration to amortize the emb sweep.
__global__ __launch_bounds__(256) void phase2_kernel(
    const float* __restrict__ z, const float* __restrict__ emb,
    const float* __restrict__ Csq, const float* __restrict__ A,
    int* __restrict__ idxbuf, const int* __restrict__ flagCount,
    const int* __restrict__ flagList) {
  __shared__ float zq[8][260];
  __shared__ float An[8];
  __shared__ int nn[8];
  __shared__ float rv[8][260];
  __shared__ int ri[8][260];
  int t = threadIdx.x;
  int cnt = *flagCount;
  int nit = (cnt + 7) >> 3;
  for (int it = blockIdx.x; it < nit; it += gridDim.x) {
    __syncthreads();
    int base = it << 3;
    int mcnt = min(8, cnt - base);
    if (t < 8) {
      if (t < mcnt) { int n = flagList[base + t]; nn[t] = n; An[t] = A[n]; }
      else nn[t] = -1;
    }
    __syncthreads();
    for (int v = 0; v < 8; ++v) {
      int n = nn[v];
      if (n >= 0) {
        int bb = n >> 10, wh = n & 1023;
        zq[v][t] = z[(((size_t)(bb * 256 + t)) << 10) + wh];
      }
    }
    __syncthreads();
    float bq[8];
    int bk[8];
#pragma unroll
    for (int v = 0; v < 8; ++v) { bq[v] = FLT_MAX; bk[v] = 0; }
    for (int r = 0; r < 4; ++r) {
      int k = t + (r << 8);
      const float4* e4 = (const float4*)(emb + ((size_t)k << 8));
      double dacc[8];
#pragma unroll
      for (int v = 0; v < 8; ++v) dacc[v] = 0.0;
      for (int d4 = 0; d4 < 64; ++d4) {
        float4 e = e4[d4];
#pragma unroll
        for (int v = 0; v < 8; ++v) {
          dacc[v] += (double)zq[v][d4 * 4 + 0] * e.x + (double)zq[v][d4 * 4 + 1] * e.y +
                     (double)zq[v][d4 * 4 + 2] * e.z + (double)zq[v][d4 * 4 + 3] * e.w;
        }
      }
      float Ck = Csq[k];
#pragma unroll
      for (int v = 0; v < 8; ++v) {
        float Bf = (float)dacc[v];
        float qv = (An[v] - 2.0f * Bf) + Ck;
        if (qv < bq[v] || (qv == bq[v] && k < bk[v])) { bq[v] = qv; bk[v] = k; }
      }
    }
#pragma unroll
    for (int v = 0; v < 8; ++v) { rv[v][t] = bq[v]; ri[v][t] = bk[v]; }
    __syncthreads();
    for (int s = 128; s > 0; s >>= 1) {
      if (t < s) {
#pragma unroll
        for (int v = 0; v < 8; ++v) {
          float ov = rv[v][t + s];
          int oi = ri[v][t + s];
          if (ov < rv[v][t] || (ov == rv[v][t] && oi < ri[v][t])) { rv[v][t] = ov; ri[v][t] = oi; }
        }
      }
      __syncthreads();
    }
    if (t < mcnt) idxbuf[nn[t]] = ri[t][0];
  }
}

// Gather + transpose: out0 = out1 = emb[idx] in [B,C,W,H]; out2 = idx as float.
__global__ __launch_bounds__(256) void gather_kernel(
    const float* __restrict__ emb, const int* __restrict__ idxbuf,
    float* __restrict__ out) {
  __shared__ int sidx[32];
  __shared__ float se[256][34];
  int tid = threadIdx.x;
  int blk = blockIdx.x;
  int n0 = blk * 32;
  int b = n0 >> 10, wh0 = n0 & 1023;
  float* out0 = out;
  float* out1 = out + 8388608;
  float* out2 = out + 16777216;
  if (tid < 32) {
    int ix = idxbuf[n0 + tid];
    sidx[tid] = ix;
    out2[n0 + tid] = (float)ix;
  }
  __syncthreads();
  {
    int v = tid >> 3, d8 = tid & 7;
    int row = sidx[v];
    const float4* e4 = (const float4*)(emb + ((size_t)row << 8));
    for (int it = 0; it < 8; ++it) {
      int d4 = it * 8 + d8;
      float4 e = e4[d4];
      se[d4 * 4 + 0][v] = e.x; se[d4 * 4 + 1][v] = e.y;
      se[d4 * 4 + 2][v] = e.z; se[d4 * 4 + 3][v] = e.w;
    }
  }
  __syncthreads();
  {
    int v = tid & 31, cg = tid >> 5;
    for (int c = cg; c < 256; c += 8) {
      float val = se[c][v];
      size_t o = (((size_t)(b * 256 + c)) << 10) + wh0 + v;
      out0[o] = val;
      out1[o] = val;
    }
  }
}

extern "C" void kernel_launch(void* const* d_in, const int* in_sizes, int n_in,
                              void* d_out, int out_size, void* d_ws, size_t ws_size,
                              hipStream_t stream) {
  const float* z = (const float*)d_in[0];
  const float* emb = (const float*)d_in[1];
  float* ws = (float*)d_ws;
  float* Csq = ws;
  float* A = ws + 1024;
  int* idxbuf = (int*)(ws + 33792);
  int* flagCount = (int*)(ws + 66560);
  int* flagList = (int*)(ws + 66576);
  unsigned short* ebf = (unsigned short*)(ws + 99344);

  precompute_kernel<<<12, 256, 0, stream>>>(emb, Csq, ebf, flagCount);
  phase1_kernel<<<512, 256, 0, stream>>>(z, ebf, Csq, A, idxbuf, flagCount, flagList);
  phase2_kernel<<<512, 256, 0, stream>>>(z, emb, Csq, A, idxbuf, flagCount, flagList);
  gather_kernel<<<1024, 256, 0, stream>>>(emb, idxbuf, (float*)d_out);
}

// Round 3
// 181.610 us; speedup vs baseline: 77.6206x; 1.2676x over previous
//
#include <hip/hip_runtime.h>
#include <cfloat>
#include <cstdint>

#define THRESH 5e-4f

typedef __attribute__((ext_vector_type(8))) short bfrag8;          // 8 bf16 (4 VGPR) MFMA A/B frag
typedef __attribute__((ext_vector_type(8))) unsigned short upk8;   // packing vector
typedef __attribute__((ext_vector_type(4))) float facc4;           // MFMA C/D frag

__device__ __forceinline__ unsigned short f2bf(float x) {
  unsigned int u = __float_as_uint(x);
  u += 0x7FFFu + ((u >> 16) & 1u);   // RNE
  return (unsigned short)(u >> 16);
}

// ws layout (float offsets):
// 0      Csq[1024]
// 1024   A[32768]           (||z||^2, written by phase1)
// 33792  idx[32768] (int)
// 66560  flagCount (int, +16 pad)
// 66576  flagList[32768] (int)
// 99344  ebf[262144] ushort (bf16 emb, 512 KB)

__global__ __launch_bounds__(256) void precompute_kernel(
    const float* __restrict__ emb, float* __restrict__ Csq,
    unsigned short* __restrict__ ebf, int* __restrict__ flagCount) {
  int blk = blockIdx.x, t = threadIdx.x;
  if (blk < 4) {
    int k = blk * 256 + t;
    const float4* e4 = (const float4*)(emb + ((size_t)k << 8));
    double acc = 0.0;
    for (int d4 = 0; d4 < 64; ++d4) {
      float4 e = e4[d4];
      acc += (double)(e.x * e.x) + (double)(e.y * e.y) +
             (double)(e.z * e.z) + (double)(e.w * e.w);
    }
    Csq[k] = (float)acc;
    if (blk == 0 && t == 0) *flagCount = 0;
  } else {
    int base = (blk - 4) * 32768;
    for (int i = base + t; i < base + 32768; i += 256) ebf[i] = f2bf(emb[i]);
  }
}

// Phase 1: bf16 MFMA GEMM-argmin. Block = 64 vectors x 1024 codes, 4 waves.
// Wave (wv,wn): 32 vectors x 64 codes per 128-code pass. s = (-2 z.e) + ||e||^2.
// A-tile za: bf16(-2z), XOR-swizzled rows (T2). Also emits A = ||z||^2.
__global__ __launch_bounds__(256, 2) void phase1_kernel(
    const float* __restrict__ z, const unsigned short* __restrict__ ebf,
    const float* __restrict__ Csq, float* __restrict__ A,
    int* __restrict__ idxbuf, int* __restrict__ flagCount,
    int* __restrict__ flagList) {
  __shared__ char za_s[64 * 512] __attribute__((aligned(16)));  // 32 KB bf16 A-tile, swizzled
  __shared__ char sbuf[33792] __attribute__((aligned(16)));     // zraw f32[128][66] / eb bf16[128][128]
  __shared__ float Cs[1024];
  __shared__ double nrm[4][64];
  __shared__ float mm1[2][2][32], mm2[2][2][32];
  __shared__ int mbi[2][2][32];

  int t = threadIdx.x;
  int n0 = blockIdx.x << 6;
  int b = n0 >> 10, wh0 = n0 & 1023;

  ((float4*)Cs)[t] = ((const float4*)Csq)[t];

  // ---- stage A: global z -> LDS transpose -> bf16(-2z) swizzled; norms for free
  float* zraw = (float*)sbuf;             // [128][66]
  int v_l = t & 63, cg = t >> 6;          // raw-load role: lanes over vectors
  int part = t & 3, vv = t >> 2;          // transpose role: 4 c-parts x 64 vectors
  double nacc = 0.0;
  for (int r = 0; r < 2; ++r) {
    __syncthreads();
    const float* zp = z + (((size_t)(b * 256 + r * 128 + cg * 32)) << 10) + wh0 + v_l;
    for (int m = 0; m < 32; ++m) zraw[(cg * 32 + m) * 66 + v_l] = zp[(size_t)m << 10];
    __syncthreads();
    for (int m = 0; m < 4; ++m) {
      int c0 = part * 32 + m * 8;
      upk8 pk;
#pragma unroll
      for (int j = 0; j < 8; ++j) {
        float x = zraw[(c0 + j) * 66 + vv];
        float y = x * x;
        nacc += (double)y;
        pk[j] = f2bf(-2.0f * x);
      }
      int bytecol = (r * 256 + c0 * 2) ^ ((vv & 7) << 4);
      *(upk8*)(za_s + (vv << 9) + bytecol) = pk;
    }
  }
  nrm[part][vv] = nacc;
  __syncthreads();
  if (t < 64) {
    double s = nrm[0][t] + nrm[1][t] + nrm[2][t] + nrm[3][t];
    A[n0 + t] = (float)s;
  }

  // ---- MFMA main loop
  char* ebc = sbuf;                        // bf16 [128 codes][128 dims], swizzled
  int w = t >> 6, l = t & 63;
  int wv = w & 1, wn = w >> 1;
  int lx = l & 15, lg = l >> 4;
  int sw = (lx & 7) << 4;                  // row&7 == lx&7 for all our rows/cols

  float m1[8], m2[8];
  int bi[8];
#pragma unroll
  for (int s8 = 0; s8 < 8; ++s8) { m1[s8] = FLT_MAX; m2[s8] = FLT_MAX; bi[s8] = 0; }

  for (int p = 0; p < 8; ++p) {
    int cp0 = p << 7;
    facc4 acc[2][4];
#pragma unroll
    for (int mi = 0; mi < 2; ++mi)
#pragma unroll
      for (int nj = 0; nj < 4; ++nj) {
        facc4 zf = {0.0f, 0.0f, 0.0f, 0.0f};
        acc[mi][nj] = zf;
      }
    for (int q = 0; q < 2; ++q) {
      __syncthreads();
#pragma unroll
      for (int i = 0; i < 8; ++i) {       // stage 128 codes x 64 dims (bf16)
        int cid = t + (i << 8);
        int cl = cid >> 4, wi = cid & 15;
        upk8 ev = *(const upk8*)(ebf + (((size_t)(cp0 + cl)) << 8) + (q << 7) + (wi << 3));
        *(upk8*)(ebc + (cl << 8) + ((wi << 4) ^ ((cl & 7) << 4))) = ev;
      }
      __syncthreads();
#pragma unroll
      for (int kk = 0; kk < 4; ++kk) {
        int ka = (q << 8) + (kk << 6) + (lg << 4);
        bfrag8 a0 = *(const bfrag8*)(za_s + ((wv * 32 + lx) << 9) + (ka ^ sw));
        bfrag8 a1 = *(const bfrag8*)(za_s + ((wv * 32 + 16 + lx) << 9) + (ka ^ sw));
        int kb = (kk << 6) + (lg << 4);
#pragma unroll
        for (int nj = 0; nj < 4; ++nj) {
          int c = wn * 64 + nj * 16 + lx;
          bfrag8 bv = *(const bfrag8*)(ebc + (c << 8) + (kb ^ sw));
          acc[0][nj] = __builtin_amdgcn_mfma_f32_16x16x32_bf16(a0, bv, acc[0][nj], 0, 0, 0);
          acc[1][nj] = __builtin_amdgcn_mfma_f32_16x16x32_bf16(a1, bv, acc[1][nj], 0, 0, 0);
        }
      }
    }
    // min-update: C/D frag (m89): col=lane&15 (code), row=lg*4+reg (vector)
    float csv[4];
#pragma unroll
    for (int nj = 0; nj < 4; ++nj) csv[nj] = Cs[cp0 + wn * 64 + nj * 16 + lx];
#pragma unroll
    for (int mi = 0; mi < 2; ++mi)
#pragma unroll
      for (int reg = 0; reg < 4; ++reg) {
        int s8 = mi * 4 + reg;
#pragma unroll
        for (int nj = 0; nj < 4; ++nj) {
          float sv = acc[mi][nj][reg] + csv[nj];
          int code = cp0 + wn * 64 + nj * 16 + lx;
          if (sv < m1[s8]) { m2[s8] = m1[s8]; m1[s8] = sv; bi[s8] = code; }
          else if (sv < m2[s8]) m2[s8] = sv;
        }
      }
  }

  // ---- reduce 16 lanes sharing each vector, then merge the two code-half waves
#pragma unroll
  for (int s8 = 0; s8 < 8; ++s8) {
    float M1 = m1[s8], M2 = m2[s8];
    int BI = bi[s8];
    for (int off = 8; off > 0; off >>= 1) {
      float om1 = __shfl_xor(M1, off, 16);
      float om2 = __shfl_xor(M2, off, 16);
      int obi = __shfl_xor(BI, off, 16);
      float lo = fminf(M2, om2);
      bool take = (om1 < M1) || (om1 == M1 && obi < BI);
      float loser = take ? M1 : om1;
      M2 = fminf(lo, loser);
      if (take) { M1 = om1; BI = obi; }
    }
    if (lx == 0) {
      int row = ((s8 >> 2) << 4) + (lg << 2) + (s8 & 3);
      mm1[wn][wv][row] = M1; mm2[wn][wv][row] = M2; mbi[wn][wv][row] = BI;
    }
  }
  __syncthreads();
  if (wn == 0 && lx == 0) {
#pragma unroll
    for (int s8 = 0; s8 < 8; ++s8) {
      int row = ((s8 >> 2) << 4) + (lg << 2) + (s8 & 3);
      float a1v = mm1[0][wv][row], a2v = mm2[0][wv][row];
      int ab = mbi[0][wv][row];
      float b1v = mm1[1][wv][row], b2v = mm2[1][wv][row];
      int bb = mbi[1][wv][row];
      bool tb = (b1v < a1v) || (b1v == a1v && bb < ab);
      float M1 = tb ? b1v : a1v;
      int BI = tb ? bb : ab;
      float M2 = fminf(fminf(a2v, b2v), tb ? a1v : b1v);
      int n = n0 + wv * 32 + row;
      idxbuf[n] = BI;
      if (M2 - M1 < THRESH) {
        int pos = atomicAdd(flagCount, 1);
        flagList[pos] = n;
      }
    }
  }
}

// Phase 2: fp32 reference-formula emulation for flagged vectors.
// q_k = fp32((A - 2*dot32) + C_k), exact compare, first-index tie-break.
// 16 vectors per block-iteration; each thread owns codes {t, t+256, t+512, t+768}.
__global__ __launch_bounds__(256) void phase2_kernel(
    const float* __restrict__ z, const float* __restrict__ emb,
    const float* __restrict__ Csq, const float* __restrict__ A,
    int* __restrict__ idxbuf, const int* __restrict__ flagCount,
    const int* __restrict__ flagList) {
  __shared__ float zq[16][260];
  __shared__ float Anv[16];
  __shared__ int nn[16];
  __shared__ float sq[16][4];
  __shared__ int sk[16][4];
  int t = threadIdx.x;
  int w = t >> 6, l = t & 63;
  int cnt = *flagCount;
  int nit = (cnt + 15) >> 4;
  for (int it = blockIdx.x; it < nit; it += gridDim.x) {
    __syncthreads();   // protect zq/nn/sq reuse across grid-stride iterations
    int base = it << 4;
    int mcnt = min(16, cnt - base);
    if (t < 16) {
      if (t < mcnt) { int n = flagList[base + t]; nn[t] = n; Anv[t] = A[n]; }
      else nn[t] = -1;
    }
    __syncthreads();
    for (int v = 0; v < 16; ++v) {
      int n = nn[v];
      if (n >= 0) {
        int bb = n >> 10, wh = n & 1023;
        zq[v][t] = z[(((size_t)(bb * 256 + t)) << 10) + wh];
      }
    }
    __syncthreads();

    float dot[4][16];
#pragma unroll
    for (int r = 0; r < 4; ++r)
#pragma unroll
      for (int v = 0; v < 16; ++v) dot[r][v] = 0.0f;

    const float4* e0 = (const float4*)(emb + ((size_t)(t + 0) << 8));
    const float4* e1 = (const float4*)(emb + ((size_t)(t + 256) << 8));
    const float4* e2 = (const float4*)(emb + ((size_t)(t + 512) << 8));
    const float4* e3 = (const float4*)(emb + ((size_t)(t + 768) << 8));
#pragma unroll 4
    for (int d4 = 0; d4 < 64; ++d4) {
      float4 ea = e0[d4], eb = e1[d4], ec = e2[d4], ed = e3[d4];
#pragma unroll
      for (int v = 0; v < 16; ++v) {
        float4 zv = *(const float4*)&zq[v][d4 * 4];
        dot[0][v] += zv.x * ea.x + zv.y * ea.y + zv.z * ea.z + zv.w * ea.w;
        dot[1][v] += zv.x * eb.x + zv.y * eb.y + zv.z * eb.z + zv.w * eb.w;
        dot[2][v] += zv.x * ec.x + zv.y * ec.y + zv.z * ec.z + zv.w * ec.w;
        dot[3][v] += zv.x * ed.x + zv.y * ed.y + zv.z * ed.z + zv.w * ed.w;
      }
    }

    float bq[16];
    int bk[16];
#pragma unroll
    for (int v = 0; v < 16; ++v) { bq[v] = FLT_MAX; bk[v] = 0; }
#pragma unroll
    for (int r = 0; r < 4; ++r) {
      int k = t + (r << 8);
      float Ck = Csq[k];
#pragma unroll
      for (int v = 0; v < 16; ++v) {
        float qv = (Anv[v] - 2.0f * dot[r][v]) + Ck;
        if (qv < bq[v]) { bq[v] = qv; bk[v] = k; }   // within-thread k ascending
      }
    }

#pragma unroll
    for (int v = 0; v < 16; ++v) {
      float q = bq[v];
      int kk = bk[v];
      for (int off = 32; off > 0; off >>= 1) {
        float oq = __shfl_xor(q, off);
        int ok = __shfl_xor(kk, off);
        if (oq < q || (oq == q && ok < kk)) { q = oq; kk = ok; }
      }
      if (l == 0) { sq[v][w] = q; sk[v][w] = kk; }
    }
    __syncthreads();
    if (t < mcnt) {
      float q = sq[t][0];
      int kk = sk[t][0];
#pragma unroll
      for (int j = 1; j < 4; ++j) {
        float oq = sq[t][j];
        int ok = sk[t][j];
        if (oq < q || (oq == q && ok < kk)) { q = oq; kk = ok; }
      }
      idxbuf[nn[t]] = kk;
    }
  }
}

// Gather + transpose: out0 = out1 = emb[idx] in [B,C,W,H]; out2 = idx as float.
__global__ __launch_bounds__(256) void gather_kernel(
    const float* __restrict__ emb, const int* __restrict__ idxbuf,
    float* __restrict__ out) {
  __shared__ int sidx[32];
  __shared__ float se[256][34];
  int tid = threadIdx.x;
  int blk = blockIdx.x;
  int n0 = blk * 32;
  int b = n0 >> 10, wh0 = n0 & 1023;
  float* out0 = out;
  float* out1 = out + 8388608;
  float* out2 = out + 16777216;
  if (tid < 32) {
    int ix = idxbuf[n0 + tid];
    sidx[tid] = ix;
    out2[n0 + tid] = (float)ix;
  }
  __syncthreads();
  {
    int v = tid >> 3, d8 = tid & 7;
    int row = sidx[v];
    const float4* e4 = (const float4*)(emb + ((size_t)row << 8));
    for (int it = 0; it < 8; ++it) {
      int d4 = it * 8 + d8;
      float4 e = e4[d4];
      se[d4 * 4 + 0][v] = e.x; se[d4 * 4 + 1][v] = e.y;
      se[d4 * 4 + 2][v] = e.z; se[d4 * 4 + 3][v] = e.w;
    }
  }
  __syncthreads();
  {
    int v = tid & 31, cg = tid >> 5;
    for (int c = cg; c < 256; c += 8) {
      float val = se[c][v];
      size_t o = (((size_t)(b * 256 + c)) << 10) + wh0 + v;
      out0[o] = val;
      out1[o] = val;
    }
  }
}

extern "C" void kernel_launch(void* const* d_in, const int* in_sizes, int n_in,
                              void* d_out, int out_size, void* d_ws, size_t ws_size,
                              hipStream_t stream) {
  const float* z = (const float*)d_in[0];
  const float* emb = (const float*)d_in[1];
  float* ws = (float*)d_ws;
  float* Csq = ws;
  float* A = ws + 1024;
  int* idxbuf = (int*)(ws + 33792);
  int* flagCount = (int*)(ws + 66560);
  int* flagList = (int*)(ws + 66576);
  unsigned short* ebf = (unsigned short*)(ws + 99344);

  precompute_kernel<<<12, 256, 0, stream>>>(emb, Csq, ebf, flagCount);
  phase1_kernel<<<512, 256, 0, stream>>>(z, ebf, Csq, A, idxbuf, flagCount, flagList);
  phase2_kernel<<<512, 256, 0, stream>>>(z, emb, Csq, A, idxbuf, flagCount, flagList);
  gather_kernel<<<1024, 256, 0, stream>>>(emb, idxbuf, (float*)d_out);
}